// Round 21
// baseline (56.459 us; speedup 1.0000x reference)
//
#include <hip/hip_runtime.h>
#include <hip/hip_fp16.h>

typedef __attribute__((ext_vector_type(8))) short f16x8;
typedef __attribute__((ext_vector_type(8))) _Float16 half8;
typedef __attribute__((ext_vector_type(4))) float f32x4;

__device__ __forceinline__ unsigned short f2h(float x) {
    __half h = __float2half(x);           // RNE f32 -> f16
    unsigned short u;
    __builtin_memcpy(&u, &h, 2);
    return u;
}

// async global->LDS, 16B per lane. LDS dest = wave-uniform base + lane*16.
__device__ __forceinline__ void gll16(const void* g, void* l) {
    __builtin_amdgcn_global_load_lds(
        (const __attribute__((address_space(1))) unsigned*)g,
        (__attribute__((address_space(3))) unsigned*)l, 16, 0, 0);
}

// ---------------- kernel 1: L2-normalize rows, f32 -> f16 (196-row panels) ----
__global__ __launch_bounds__(256) void norm_kernel(
    const float* __restrict__ feats, const float* __restrict__ nfeats,
    unsigned short* __restrict__ fH, unsigned short* __restrict__ nfH)
{
    int row  = blockIdx.x * 4 + (threadIdx.x >> 6);    // one wave per row, rows 0..18815
    int lane = threadIdx.x & 63;
    const float* src;
    unsigned short* dst;
    if (row < 6272) { src = feats  + (size_t)row * 128; dst = fH  + (size_t)row * 128; }
    else { int r2 = row - 6272; src = nfeats + (size_t)r2 * 128; dst = nfH + (size_t)r2 * 128; }

    float2 v = *(const float2*)(src + lane * 2);
    float ss = v.x * v.x + v.y * v.y;
    #pragma unroll
    for (int m = 1; m < 64; m <<= 1) ss += __shfl_xor(ss, m, 64);
    float rn = rsqrtf(ss);
    ushort2 o; o.x = f2h(v.x * rn); o.y = f2h(v.y * rn);
    *(ushort2*)(dst + lane * 2) = o;
}

// ---------------- kernel 2: global pb[4], double-buffered B, 16 waves/block ----
// Stage a 196x128 f16 panel (3136 16B chunks), source-side swizzled:
// LDS slot (row, cc) holds global chunk (row, cc ^ (row&7)).  1024 threads.
__device__ __forceinline__ void stage1024(const f16x8* __restrict__ g, f16x8* l,
                                          int tid, int wave) {
    #pragma unroll
    for (int i = 0; i < 3; ++i) {
        int slot = i * 1024 + tid;
        int row = slot >> 4, cc = slot & 15;
        gll16(g + row * 16 + (cc ^ (row & 7)), l + i * 1024 + wave * 64);
    }
    if (tid < 64) {                        // tail: slots 3072..3135 (rows 192..195)
        int slot = 3072 + tid;
        int row = slot >> 4, cc = slot & 15;
        gll16(g + row * 16 + (cc ^ (row & 7)), l + 3072);
    }
}

__global__ __launch_bounds__(1024, 4) void simmax_kernel(
    const unsigned short* __restrict__ fH, const unsigned short* __restrict__ nfH,
    const float* __restrict__ mask, float* __restrict__ sp, float* __restrict__ scores)
{
    __shared__ f16x8 Bbuf[2][3136];       // double-buffered B: 100,352 B
    __shared__ unsigned smaxL[8 * 208];   // per-(bi, p) running max of sim+3
    __shared__ unsigned scoresL[8];

    int a = blockIdx.x & 31, bg = blockIdx.x >> 5;   // 256 blocks = 1/CU
    int b0 = bg * 8;
    int tid = threadIdx.x, wave = tid >> 6, lane = tid & 63;
    int l15 = lane & 15, lg = lane >> 4;  // fragment row / k-group
    int pg = wave & 3, qs = wave >> 2;    // SIMD = wave&3 hosts one pg x all 13 qi
    const int p0tab[4] = {0, 64, 128, 132};   // 4 tiles each; pg2/pg3 overlap (max-idem)
    int p0 = p0tab[pg];
    const int qstart[4] = {0, 4, 7, 10};
    const int qend[4]   = {4, 7, 10, 13};

    for (int i = tid; i < 8 * 208; i += 1024) smaxL[i] = 0u;
    if (tid < 8) scoresL[tid] = 0u;

    // P fragments: 4 p-tiles x 4 ks (64 VGPR) from GLOBAL via volatile asm
    // (r15/r19-proven resident). 128-reg budget at (1024,4): pb 64 + acc 16
    // + misc fits. r18/r20 died at pb-128/budget-128 squeezes -- never again.
    // lane: row p0+pt*16+l15, k = ks*32 + lg*8 + j.
    const unsigned short* fb = fH + (size_t)a * 196 * 128 + l15 * 128 + lg * 8;
    half8 pb[4][4];
    #pragma unroll
    for (int pt = 0; pt < 4; ++pt) {
        #pragma unroll
        for (int ks = 0; ks < 4; ++ks) {
            const unsigned short* ad = fb + (p0 + pt * 16) * 128 + ks * 32;
            asm volatile("global_load_dwordx4 %0, %1, off" : "=&v"(pb[pt][ks]) : "v"(ad));
        }
    }
    asm volatile("s_waitcnt vmcnt(0)"
        : "+v"(pb[0][0]), "+v"(pb[0][1]), "+v"(pb[0][2]), "+v"(pb[0][3]),
          "+v"(pb[1][0]), "+v"(pb[1][1]), "+v"(pb[1][2]), "+v"(pb[1][3]),
          "+v"(pb[2][0]), "+v"(pb[2][1]), "+v"(pb[2][2]), "+v"(pb[2][3]),
          "+v"(pb[3][0]), "+v"(pb[3][1]), "+v"(pb[3][2]), "+v"(pb[3][3]));
    __builtin_amdgcn_sched_barrier(0);    // no motion across the drain point

    stage1024((const f16x8*)(nfH + (size_t)b0 * 196 * 128), Bbuf[0], tid, wave);
    __syncthreads();                      // B0 staged; smaxL zeroing visible

    for (int bi = 0; bi < 8; ++bi) {
        f16x8* Bcur = Bbuf[bi & 1];
        f16x8* Bnxt = Bbuf[(bi & 1) ^ 1];
        if (bi < 7)                       // async; lands during this bi's compute
            stage1024((const f16x8*)(nfH + (size_t)(b0 + bi + 1) * 196 * 128), Bnxt, tid, wave);

        float rmax[4];
        #pragma unroll
        for (int pt = 0; pt < 4; ++pt) rmax[pt] = -3.0f;

        for (int qi = qstart[qs]; qi < qend[qs]; ++qi) {
            int qbase = (qi < 12) ? qi * 16 : 180;   // tile 12 @180: rows all valid
            f32x4 acc[4];
            #pragma unroll
            for (int pt = 0; pt < 4; ++pt) acc[pt] = (f32x4){0.f, 0.f, 0.f, 0.f};
            #pragma unroll
            for (int ks = 0; ks < 4; ++ks) {
                int row = qbase + l15;
                half8 qa = *(const half8*)(Bcur + ((row << 4) | ((ks * 4 + lg) ^ (row & 7))));
                #pragma unroll
                for (int pt = 0; pt < 4; ++pt)
                    acc[pt] = __builtin_amdgcn_mfma_f32_16x16x32_f16(qa, pb[pt][ks], acc[pt], 0, 0, 0);
            }
            // C/D: col = lane&15 = p, row = q = 4*lg + reg. Fold 4 q's per lane.
            #pragma unroll
            for (int pt = 0; pt < 4; ++pt)
                rmax[pt] = fmaxf(rmax[pt],
                           fmaxf(fmaxf(acc[pt][0], acc[pt][1]),
                                 fmaxf(acc[pt][2], acc[pt][3])));
        }
        // merge lane-groups in-wave, then one conflict-free atomic from lg==0
        #pragma unroll
        for (int pt = 0; pt < 4; ++pt) {
            float v = rmax[pt];
            v = fmaxf(v, __shfl_xor(v, 16, 64));
            v = fmaxf(v, __shfl_xor(v, 32, 64));
            if (lg == 0)
                atomicMax(&smaxL[bi * 208 + p0 + pt * 16 + l15],
                          __float_as_uint(v + 3.0f));   // sim+3 > 0
        }
        __syncthreads();                  // Bcur free for re-stage; Bnxt drained
    }

    // epilogue: one thread per p (waves 0-3), all 8 bi at once
    if (tid < 256) {
        int p = tid;
        float mk = (p < 196) ? mask[a * 196 + p] : 0.0f;
        float d8[8];
        #pragma unroll
        for (int bi = 0; bi < 8; ++bi) {
            float d = 0.0f;
            if (p < 196) {
                float sim = __uint_as_float(smaxL[bi * 208 + p]) - 3.0f;
                d = 0.5f * sqrtf(fmaxf(2.0f - 2.0f * sim, 0.0f)) * mk;
            }
            d8[bi] = d;
            float m = d;                  // per-b max over this wave's 64 p's
            #pragma unroll
            for (int s = 1; s < 64; s <<= 1) m = fmaxf(m, __shfl_xor(m, s, 64));
            if (lane == 0) atomicMax(&scoresL[bi], __float_as_uint(m));
        }
        if (p < 196) {
            float* dst = sp + ((size_t)a * 196 + p) * 64 + b0;
            *(f32x4*)(dst)     = (f32x4){d8[0], d8[1], d8[2], d8[3]};
            *(f32x4*)(dst + 4) = (f32x4){d8[4], d8[5], d8[6], d8[7]};
        }
    }
    __syncthreads();
    if (tid < 8)                          // block exclusively owns (a, b0+tid)
        scores[a * 64 + b0 + tid] = __uint_as_float(scoresL[tid]);
}

// ---------------- kernel 3: patch mean over b + scores mean ----
__global__ __launch_bounds__(256) void patchmean_kernel(
    const float* __restrict__ sp, const float* __restrict__ scores,
    float* __restrict__ patch, float* __restrict__ out)
{
    int a = blockIdx.x, tid = threadIdx.x;
    if (tid < 196) {
        const f32x4* v = (const f32x4*)(sp + ((size_t)a * 196 + tid) * 64);
        float s = 0.0f;
        #pragma unroll
        for (int j = 0; j < 16; ++j) { f32x4 x = v[j]; s += x[0] + x[1] + x[2] + x[3]; }
        patch[a * 196 + tid] = s * (1.0f / 64.0f);
    }
    if (tid >= 192 && tid < 256) {         // wave 3: scores mean
        int l = tid - 192;
        float s = scores[a * 64 + l];
        #pragma unroll
        for (int m = 1; m < 64; m <<= 1) s += __shfl_xor(s, m, 64);
        if (l == 0) out[a] = s * (1.0f / 64.0f);
    }
}

// ---------------- kernel 4: bilinear 14x14 -> 224x224, 8-row bands ----
__global__ __launch_bounds__(256) void upsample_kernel(
    const float* __restrict__ patch, float* __restrict__ out)
{
    int bid = blockIdx.x;
    int a = bid / 28, band = bid % 28;
    __shared__ float pt[196];
    if (threadIdx.x < 196) pt[threadIdx.x] = patch[a * 196 + threadIdx.x];
    __syncthreads();

    float* op = out + 32 + (size_t)a * 50176 + band * 8 * 224;
    for (int t = threadIdx.x; t < 8 * 224; t += 256) {
        int h = band * 8 + (t / 224), w = t % 224;
        float sh = fmaxf((h + 0.5f) * 0.0625f - 0.5f, 0.0f);   // 14/224 = 1/16
        float sw = fmaxf((w + 0.5f) * 0.0625f - 0.5f, 0.0f);
        int h0 = (int)sh, w0 = (int)sw;
        int h1 = min(h0 + 1, 13), w1 = min(w0 + 1, 13);
        float fh = sh - (float)h0, fw = sw - (float)w0;
        float v00 = pt[h0 * 14 + w0], v01 = pt[h0 * 14 + w1];
        float v10 = pt[h1 * 14 + w0], v11 = pt[h1 * 14 + w1];
        op[t] = (1.0f - fh) * ((1.0f - fw) * v00 + fw * v01)
              +         fh  * ((1.0f - fw) * v10 + fw * v11);
    }
}

extern "C" void kernel_launch(void* const* d_in, const int* in_sizes, int n_in,
                              void* d_out, int out_size, void* d_ws, size_t ws_size,
                              hipStream_t stream) {
    const float* feats  = (const float*)d_in[0];   // [32,196,128]
    const float* nfeats = (const float*)d_in[1];   // [64,196,128]
    const float* mask   = (const float*)d_in[2];   // [32,196]
    float* out = (float*)d_out;                    // 32 + 32*224*224

    char* w = (char*)d_ws;
    unsigned short* fH  = (unsigned short*)(w);            // 32*196*128 f16 = 1,605,632 B
    unsigned short* nfH = (unsigned short*)(w + 1605632);  // 64*196*128 f16 = 3,211,264 B
    float* sp     = (float*)(w + 4816896);                 // 32*196*64 f32  = 1,605,632 B
    float* scores = (float*)(w + 6422528);                 // 2048 f32
    float* patch  = (float*)(w + 6430720);                 // 32*196 f32

    norm_kernel<<<4704, 256, 0, stream>>>(feats, nfeats, fH, nfH);
    simmax_kernel<<<256, 1024, 0, stream>>>(fH, nfH, mask, sp, scores);
    patchmean_kernel<<<32, 256, 0, stream>>>(sp, scores, patch, out);
    upsample_kernel<<<896, 256, 0, stream>>>(patch, out);
}

// Round 22
// 46.245 us; speedup vs baseline: 1.2209x; 1.2209x over previous
//
#include <hip/hip_runtime.h>
#include <hip/hip_fp16.h>

typedef __attribute__((ext_vector_type(8))) short f16x8;
typedef __attribute__((ext_vector_type(8))) _Float16 half8;
typedef __attribute__((ext_vector_type(4))) float f32x4;

__device__ __forceinline__ unsigned short f2h(float x) {
    __half h = __float2half(x);           // RNE f32 -> f16
    unsigned short u;
    __builtin_memcpy(&u, &h, 2);
    return u;
}

// async global->LDS, 16B per lane. LDS dest = wave-uniform base + lane*16.
__device__ __forceinline__ void gll16(const void* g, void* l) {
    __builtin_amdgcn_global_load_lds(
        (const __attribute__((address_space(1))) unsigned*)g,
        (__attribute__((address_space(3))) unsigned*)l, 16, 0, 0);
}

// ---------------- kernel 1: L2-normalize rows, f32 -> f16 (196-row panels) ----
__global__ __launch_bounds__(256) void norm_kernel(
    const float* __restrict__ feats, const float* __restrict__ nfeats,
    unsigned short* __restrict__ fH, unsigned short* __restrict__ nfH)
{
    int row  = blockIdx.x * 4 + (threadIdx.x >> 6);    // one wave per row, rows 0..18815
    int lane = threadIdx.x & 63;
    const float* src;
    unsigned short* dst;
    if (row < 6272) { src = feats  + (size_t)row * 128; dst = fH  + (size_t)row * 128; }
    else { int r2 = row - 6272; src = nfeats + (size_t)r2 * 128; dst = nfH + (size_t)r2 * 128; }

    float2 v = *(const float2*)(src + lane * 2);
    float ss = v.x * v.x + v.y * v.y;
    #pragma unroll
    for (int m = 1; m < 64; m <<= 1) ss += __shfl_xor(ss, m, 64);
    float rn = rsqrtf(ss);
    ushort2 o; o.x = f2h(v.x * rn); o.y = f2h(v.y * rn);
    *(ushort2*)(dst + lane * 2) = o;
}

// ---------------- kernel 2: r16 chassis + hoisted lane-const addressing ----
// Stage a 196x128 f16 panel (3136 16B chunks), source-side swizzled:
// LDS slot (row, cc) holds global chunk (row, cc ^ (row&7)).  512 threads.
__device__ __forceinline__ void stage196(const f16x8* __restrict__ g, f16x8* l,
                                         int tid, int wave) {
    #pragma unroll
    for (int i = 0; i < 6; ++i) {
        int slot = i * 512 + tid;
        int row = slot >> 4, cc = slot & 15;
        gll16(g + row * 16 + (cc ^ (row & 7)), l + i * 512 + wave * 64);
    }
    if (tid < 64) {                        // tail: slots 3072..3135 (rows 192..195)
        int slot = 3072 + tid;
        int row = slot >> 4, cc = slot & 15;
        gll16(g + row * 16 + (cc ^ (row & 7)), l + 3072);
    }
}

// fold 4 acc regs into rmax via 2 x v_max3 (nested fmax triples fuse)
#define FOLD8(ACC, RMAX)                                                      \
    _Pragma("unroll")                                                         \
    for (int pt = 0; pt < 8; ++pt) {                                          \
        float t = fmaxf(fmaxf(ACC[pt][0], ACC[pt][1]), ACC[pt][2]);           \
        RMAX[pt] = fmaxf(fmaxf(ACC[pt][3], t), RMAX[pt]);                     \
    }

__global__ __launch_bounds__(512, 2) void simmax_kernel(
    const unsigned short* __restrict__ fH, const unsigned short* __restrict__ nfH,
    const float* __restrict__ mask, float* __restrict__ sp, float* __restrict__ scores)
{
    __shared__ f16x8 lds[3 * 3136];       // F | B0 | B1 = 150,528 B
    __shared__ unsigned smaxL[8 * 208];   // per-(bi, p) running max of sim+3
    __shared__ unsigned scoresL[8];
    f16x8* Fl = lds;
    f16x8* B0 = lds + 3136;
    f16x8* B1 = lds + 6272;

    int a = blockIdx.x & 31, bg = blockIdx.x >> 5;   // 256 blocks = 1/CU
    int b0 = bg * 8;
    int tid = threadIdx.x, wave = tid >> 6, lane = tid & 63;
    int l15 = lane & 15, lg = lane >> 4;             // fragment row / k-group
    int pg = wave & 1, qs = wave >> 1;               // p-group (2), q-subset (4)
    int p0 = pg ? 68 : 0;                            // p-tiles p0+16*pt, pt=0..7
    const int qstart[4] = {0, 4, 7, 10};
    const int qend[4]   = {4, 7, 10, 13};

    // Hoisted lane-const byte offsets. Every row base is 0 or 4 (mod 8)
    // (qbase in {16k, 180}, p0 in {0,68}) so the swizzle term is lane-const:
    // addr = uniform(base*256) + loffX[ks], one v_add per LDS read.
    int loff0[4], loff4[4];
    #pragma unroll
    for (int ks = 0; ks < 4; ++ks) {
        loff0[ks] = l15 * 256 + (((ks * 4 + lg) ^ (l15 & 7)) << 4);
        loff4[ks] = l15 * 256 + (((ks * 4 + lg) ^ ((l15 + 4) & 7)) << 4);
    }

    stage196((const f16x8*)(fH  + (size_t)a  * 196 * 128), Fl, tid, wave);
    stage196((const f16x8*)(nfH + (size_t)b0 * 196 * 128), B0, tid, wave);
    for (int i = tid; i < 8 * 208; i += 512) smaxL[i] = 0u;
    if (tid < 8) scoresL[tid] = 0u;
    __syncthreads();                      // panels staged, accumulators zeroed

    // P fragments: 8 p-tiles x 4 ks from the LDS F-panel (cheap hoisted addr).
    const char* Fb = (const char*)Fl;
    half8 pb[8][4];
    #pragma unroll
    for (int pt = 0; pt < 8; ++pt) {
        int poff = (p0 + pt * 16) * 256;
        #pragma unroll
        for (int ks = 0; ks < 4; ++ks) {
            int lo = pg ? loff4[ks] : loff0[ks];
            pb[pt][ks] = *(const half8*)(Fb + poff + lo);
            asm volatile("" : "+v"(pb[pt][ks]));     // value pass-through pin
        }
    }
    asm volatile("" ::: "memory");        // remat firewall (best-effort)

    for (int bi = 0; bi < 8; ++bi) {
        f16x8* Bcur = (bi & 1) ? B1 : B0;
        f16x8* Bnxt = (bi & 1) ? B0 : B1;
        if (bi < 7)                       // async; lands during this bi's compute
            stage196((const f16x8*)(nfH + (size_t)(b0 + bi + 1) * 196 * 128), Bnxt, tid, wave);

        const char* Bb = (const char*)Bcur;
        float rmax[8];
        #pragma unroll
        for (int pt = 0; pt < 8; ++pt) rmax[pt] = -3.0f;

        int q1 = (qend[qs] < 12) ? qend[qs] : 12;
        for (int qi = qstart[qs]; qi < q1; ++qi) {   // regular tiles (base%8==0)
            int qoff = qi * 4096;                    // qbase*256, uniform
            f32x4 acc[8];
            #pragma unroll
            for (int pt = 0; pt < 8; ++pt) acc[pt] = (f32x4){0.f, 0.f, 0.f, 0.f};
            #pragma unroll
            for (int ks = 0; ks < 4; ++ks) {
                half8 qa = *(const half8*)(Bb + qoff + loff0[ks]);
                #pragma unroll
                for (int pt = 0; pt < 8; ++pt)
                    acc[pt] = __builtin_amdgcn_mfma_f32_16x16x32_f16(qa, pb[pt][ks], acc[pt], 0, 0, 0);
            }
            FOLD8(acc, rmax)
        }
        if (qs == 3) {                    // tile 12 @180 (base%8==4), rows valid
            f32x4 acc[8];
            #pragma unroll
            for (int pt = 0; pt < 8; ++pt) acc[pt] = (f32x4){0.f, 0.f, 0.f, 0.f};
            #pragma unroll
            for (int ks = 0; ks < 4; ++ks) {
                half8 qa = *(const half8*)(Bb + 46080 + loff4[ks]);
                #pragma unroll
                for (int pt = 0; pt < 8; ++pt)
                    acc[pt] = __builtin_amdgcn_mfma_f32_16x16x32_f16(qa, pb[pt][ks], acc[pt], 0, 0, 0);
            }
            FOLD8(acc, rmax)
        }

        // merge the 4 lane-groups (q rows) via 4-way same-address LDS atomic
        #pragma unroll
        for (int pt = 0; pt < 8; ++pt)
            atomicMax(&smaxL[bi * 208 + p0 + pt * 16 + l15],
                      __float_as_uint(rmax[pt] + 3.0f));   // sim+3 > 0

        __syncthreads();                  // Bcur free for re-stage; Bnxt drained
    }

    // epilogue: one thread per p (waves 0-3), all 8 bi at once
    if (wave < 4) {
        int p = tid;                      // 0..255; valid p < 196
        float mk = (p < 196) ? mask[a * 196 + p] : 0.0f;
        float d8[8];
        #pragma unroll
        for (int bi = 0; bi < 8; ++bi) {
            float d = 0.0f;
            if (p < 196) {
                float sim = __uint_as_float(smaxL[bi * 208 + p]) - 3.0f;
                d = 0.5f * sqrtf(fmaxf(2.0f - 2.0f * sim, 0.0f)) * mk;
            }
            d8[bi] = d;
            float m = d;                  // per-b max over this wave's 64 p's
            #pragma unroll
            for (int s = 1; s < 64; s <<= 1) m = fmaxf(m, __shfl_xor(m, s, 64));
            if (lane == 0) atomicMax(&scoresL[bi], __float_as_uint(m));
        }
        if (p < 196) {
            float* dst = sp + ((size_t)a * 196 + p) * 64 + b0;
            *(f32x4*)(dst)     = (f32x4){d8[0], d8[1], d8[2], d8[3]};
            *(f32x4*)(dst + 4) = (f32x4){d8[4], d8[5], d8[6], d8[7]};
        }
    }
    __syncthreads();
    if (tid < 8)                          // block exclusively owns (a, b0+tid)
        scores[a * 64 + b0 + tid] = __uint_as_float(scoresL[tid]);
}

// ---------------- kernel 3: patch mean over b + scores mean ----
__global__ __launch_bounds__(256) void patchmean_kernel(
    const float* __restrict__ sp, const float* __restrict__ scores,
    float* __restrict__ patch, float* __restrict__ out)
{
    int a = blockIdx.x, tid = threadIdx.x;
    if (tid < 196) {
        const f32x4* v = (const f32x4*)(sp + ((size_t)a * 196 + tid) * 64);
        float s = 0.0f;
        #pragma unroll
        for (int j = 0; j < 16; ++j) { f32x4 x = v[j]; s += x[0] + x[1] + x[2] + x[3]; }
        patch[a * 196 + tid] = s * (1.0f / 64.0f);
    }
    if (tid >= 192 && tid < 256) {         // wave 3: scores mean
        int l = tid - 192;
        float s = scores[a * 64 + l];
        #pragma unroll
        for (int m = 1; m < 64; m <<= 1) s += __shfl_xor(s, m, 64);
        if (l == 0) out[a] = s * (1.0f / 64.0f);
    }
}

// ---------------- kernel 4: bilinear 14x14 -> 224x224, 8-row bands ----
__global__ __launch_bounds__(256) void upsample_kernel(
    const float* __restrict__ patch, float* __restrict__ out)
{
    int bid = blockIdx.x;
    int a = bid / 28, band = bid % 28;
    __shared__ float pt[196];
    if (threadIdx.x < 196) pt[threadIdx.x] = patch[a * 196 + threadIdx.x];
    __syncthreads();

    float* op = out + 32 + (size_t)a * 50176 + band * 8 * 224;
    for (int t = threadIdx.x; t < 8 * 224; t += 256) {
        int h = band * 8 + (t / 224), w = t % 224;
        float sh = fmaxf((h + 0.5f) * 0.0625f - 0.5f, 0.0f);   // 14/224 = 1/16
        float sw = fmaxf((w + 0.5f) * 0.0625f - 0.5f, 0.0f);
        int h0 = (int)sh, w0 = (int)sw;
        int h1 = min(h0 + 1, 13), w1 = min(w0 + 1, 13);
        float fh = sh - (float)h0, fw = sw - (float)w0;
        float v00 = pt[h0 * 14 + w0], v01 = pt[h0 * 14 + w1];
        float v10 = pt[h1 * 14 + w0], v11 = pt[h1 * 14 + w1];
        op[t] = (1.0f - fh) * ((1.0f - fw) * v00 + fw * v01)
              +         fh  * ((1.0f - fw) * v10 + fw * v11);
    }
}

extern "C" void kernel_launch(void* const* d_in, const int* in_sizes, int n_in,
                              void* d_out, int out_size, void* d_ws, size_t ws_size,
                              hipStream_t stream) {
    const float* feats  = (const float*)d_in[0];   // [32,196,128]
    const float* nfeats = (const float*)d_in[1];   // [64,196,128]
    const float* mask   = (const float*)d_in[2];   // [32,196]
    float* out = (float*)d_out;                    // 32 + 32*224*224

    char* w = (char*)d_ws;
    unsigned short* fH  = (unsigned short*)(w);            // 32*196*128 f16 = 1,605,632 B
    unsigned short* nfH = (unsigned short*)(w + 1605632);  // 64*196*128 f16 = 3,211,264 B
    float* sp     = (float*)(w + 4816896);                 // 32*196*64 f32  = 1,605,632 B
    float* scores = (float*)(w + 6422528);                 // 2048 f32
    float* patch  = (float*)(w + 6430720);                 // 32*196 f32

    norm_kernel<<<4704, 256, 0, stream>>>(feats, nfeats, fH, nfH);
    simmax_kernel<<<256, 512, 0, stream>>>(fH, nfH, mask, sp, scores);
    patchmean_kernel<<<32, 256, 0, stream>>>(sp, scores, patch, out);
    upsample_kernel<<<896, 256, 0, stream>>>(patch, out);
}